// Round 5
// baseline (49.243 us; speedup 1.0000x reference)
//
#include <hip/hip_runtime.h>
#include <math.h>

// QNN forward, single fused kernel, 2 samples/thread.
// DIAGNOSTIC ROUND: kernel launched TWICE (identical work, identical output,
// deterministic) to measure the marginal steady-state kernel cost vs the
// fixed graph/launch overhead. dur_delta == true kernel time.
//
// cons layout (floats):
//   [0..31]  gates: qubit q at 8q: {g00r,g00i,g01r,g01i,g10r,g10i,g11r,g11i}
//   [32..79] wv[3][16] (CNOT-permuted Z/fc_w contraction weights)
//   [80..82] fc_b

#define QNN_BATCH 1048576

__device__ __forceinline__ int qnn_cnot_perm(int k, int c, int t) {
    int cbit = 1 << (3 - c), tbit = 1 << (3 - t);
    return (k & cbit) ? (k ^ tbit) : k;
}

// Complex butterfly stage with stride S (gate at G), in-place on yr/yi.
#define QNN_CSTAGE(S, G)                                                        \
    do {                                                                        \
        const float g00r=(G)[0], g00i=(G)[1], g01r=(G)[2], g01i=(G)[3];         \
        const float g10r=(G)[4], g10i=(G)[5], g11r=(G)[6], g11i=(G)[7];         \
        _Pragma("unroll")                                                       \
        for (int base = 0; base < 16; base += 2 * (S)) {                        \
            _Pragma("unroll")                                                   \
            for (int k = 0; k < (S); ++k) {                                     \
                const int j0 = base + k, j1 = j0 + (S);                         \
                const float ar = yr[j0], ai = yi[j0];                           \
                const float br = yr[j1], bi = yi[j1];                           \
                yr[j0] = fmaf(g00r, ar, fmaf(-g00i, ai, fmaf(g01r, br, -g01i * bi))); \
                yi[j0] = fmaf(g00r, ai, fmaf( g00i, ar, fmaf(g01r, bi,  g01i * br))); \
                yr[j1] = fmaf(g10r, ar, fmaf(-g10i, ai, fmaf(g11r, br, -g11i * bi))); \
                yi[j1] = fmaf(g10r, ai, fmaf( g10i, ar, fmaf(g11r, bi,  g11i * br))); \
            }                                                                   \
        }                                                                       \
    } while (0)

__device__ __forceinline__ void qnn_one(const float xv[16], const float* cons,
                                        float* l0, float* l1, float* l2) {
    float n2 = 0.f;
#pragma unroll
    for (int i = 0; i < 16; ++i) n2 = fmaf(xv[i], xv[i], n2);

    float yr[16], yi[16];
    // Stage qubit 0 (stride 8), real input.
    {
        const float g00r = cons[0], g00i = cons[1], g01r = cons[2], g01i = cons[3];
        const float g10r = cons[4], g10i = cons[5], g11r = cons[6], g11i = cons[7];
#pragma unroll
        for (int k = 0; k < 8; ++k) {
            const float a = xv[k], b = xv[k + 8];
            yr[k]     = fmaf(g00r, a, g01r * b);
            yi[k]     = fmaf(g00i, a, g01i * b);
            yr[k + 8] = fmaf(g10r, a, g11r * b);
            yi[k + 8] = fmaf(g10i, a, g11i * b);
        }
    }
    QNN_CSTAGE(4, cons + 8);   // qubit 1
    QNN_CSTAGE(2, cons + 16);  // qubit 2
    QNN_CSTAGE(1, cons + 24);  // qubit 3

    float acc0 = 0.f, acc1 = 0.f, acc2 = 0.f;
#pragma unroll
    for (int j = 0; j < 16; ++j) {
        const float p = fmaf(yr[j], yr[j], yi[j] * yi[j]);
        acc0 = fmaf(cons[32 + j], p, acc0);
        acc1 = fmaf(cons[48 + j], p, acc1);
        acc2 = fmaf(cons[64 + j], p, acc2);
    }
    const float inv = 1.0f / n2;
    *l0 = fmaf(acc0, inv, cons[80]);
    *l1 = fmaf(acc1, inv, cons[81]);
    *l2 = fmaf(acc2, inv, cons[82]);
}

__global__ __launch_bounds__(256) void qnn_fused(const float* __restrict__ x,
                                                 const float* __restrict__ params,
                                                 const float* __restrict__ fc_w,
                                                 const float* __restrict__ fc_b,
                                                 float* __restrict__ out) {
    __shared__ float cons[84];

    const int t = blockIdx.x * 256 + threadIdx.x;
    const size_t s0 = (size_t)t * 2;  // two consecutive samples per thread

    // Issue ALL global loads up front (8 x dwordx4, 128 B/thread, dense).
    const float4* xp = (const float4*)(x + s0 * 16);
    float4 v[8];
#pragma unroll
    for (int k = 0; k < 8; ++k) v[k] = xp[k];

    // Thread 0 computes shared constants while loads are in flight.
    if (threadIdx.x == 0) {
        for (int q = 0; q < 4; ++q) {
            float hx = 0.5f * params[q * 3 + 0];
            float hy = 0.5f * params[q * 3 + 1];
            float hz = 0.5f * params[q * 3 + 2];
            float cx = cosf(hx), sx = sinf(hx);
            float cy = cosf(hy), sy = sinf(hy);
            float cz = cosf(hz), sz = sinf(hz);
            float A = cy * cx, B = sy * sx, C = sy * cx, D = cy * sx;
            float* g = cons + q * 8;
            g[0] =  cz * A + sz * B;   // g00 re
            g[1] =  cz * B - sz * A;   // g00 im
            g[2] = -cz * C - sz * D;   // g01 re
            g[3] =  sz * C - cz * D;   // g01 im
            g[4] =  cz * C + sz * D;   // g10 re
            g[5] =  sz * C - cz * D;   // g10 im
            g[6] =  cz * A + sz * B;   // g11 re
            g[7] =  sz * A - cz * B;   // g11 im
        }
        // wv[c][q(o)] = sum_w fc_w[c,w] * zsign(o,w);  q = p01 o p12 o p23
        for (int o = 0; o < 16; ++o) {
            int j = qnn_cnot_perm(qnn_cnot_perm(qnn_cnot_perm(o, 2, 3), 1, 2), 0, 1);
            for (int c = 0; c < 3; ++c) {
                float s = 0.f;
                for (int ww = 0; ww < 4; ++ww) {
                    float z = 1.f - 2.f * (float)((o >> (3 - ww)) & 1);
                    s += fc_w[c * 4 + ww] * z;
                }
                cons[32 + c * 16 + j] = s;
            }
        }
        for (int c = 0; c < 3; ++c) cons[80 + c] = fc_b[c];
    }
    __syncthreads();

    float xa[16], xb[16];
#pragma unroll
    for (int k = 0; k < 4; ++k) {
        xa[k * 4 + 0] = v[k].x;     xa[k * 4 + 1] = v[k].y;
        xa[k * 4 + 2] = v[k].z;     xa[k * 4 + 3] = v[k].w;
        xb[k * 4 + 0] = v[k + 4].x; xb[k * 4 + 1] = v[k + 4].y;
        xb[k * 4 + 2] = v[k + 4].z; xb[k * 4 + 3] = v[k + 4].w;
    }

    float a0, a1, a2, b0, b1, b2;
    qnn_one(xa, cons, &a0, &a1, &a2);
    qnn_one(xb, cons, &b0, &b1, &b2);

    // 6 contiguous floats per thread; 24 B offset keeps float2 alignment.
    float2* o = (float2*)(out + s0 * 3);
    o[0] = make_float2(a0, a1);
    o[1] = make_float2(a2, b0);
    o[2] = make_float2(b1, b2);
}

extern "C" void kernel_launch(void* const* d_in, const int* in_sizes, int n_in,
                              void* d_out, int out_size, void* d_ws, size_t ws_size,
                              hipStream_t stream) {
    (void)in_sizes; (void)n_in; (void)out_size; (void)d_ws; (void)ws_size;
    const float* x      = (const float*)d_in[0];
    const float* params = (const float*)d_in[1];
    const float* fc_w   = (const float*)d_in[2];
    const float* fc_b   = (const float*)d_in[3];
    float* out = (float*)d_out;

    // DIAGNOSTIC: two identical launches. Marginal cost of the 2nd launch
    // == true steady-state kernel time (x L3-resident, same as timed replays).
    qnn_fused<<<QNN_BATCH / 512, 256, 0, stream>>>(x, params, fc_w, fc_b, out);
    qnn_fused<<<QNN_BATCH / 512, 256, 0, stream>>>(x, params, fc_w, fc_b, out);
}

// Round 6
// 28.234 us; speedup vs baseline: 1.7441x; 1.7441x over previous
//
#include <hip/hip_runtime.h>
#include <math.h>

// QNN forward, single fused kernel, 1 sample/thread, low-VGPR/high-occupancy:
//   logits[b,c] = fc_b[c] + (sum_j wv[c][j] * |psi_j|^2) / ||x_b||^2
//   psi = (U0 (x) U1 (x) U2 (x) U3) @ x_b   (CNOT row-perm folded into wv)
//
// R6 theory: prior rounds stalled on FMA dep chains at 2-4 waves/SIMD.
// This version: in-place stages (peak ~70 VGPR), __launch_bounds__(256,6)
// -> 6 waves/SIMD, tree-split reductions, float4 LDS constant reads.
//
// cons layout (floats):
//   [0..31]  gates: qubit q at 8q: {g00r,g00i,g01r,g01i,g10r,g10i,g11r,g11i}
//   [32..79] wv[3][16] (CNOT-permuted Z/fc_w contraction weights)
//   [80..82] fc_b

#define QNN_BATCH 1048576

__device__ __forceinline__ int qnn_cnot_perm(int k, int c, int t) {
    int cbit = 1 << (3 - c), tbit = 1 << (3 - t);
    return (k & cbit) ? (k ^ tbit) : k;
}

// Complex butterfly stage with stride S (gate float4s ga={g00r,g00i,g01r,g01i},
// gb={g10r,g10i,g11r,g11i}), in-place on yr/yi.
#define QNN_CSTAGE(S, ga, gb)                                                   \
    do {                                                                        \
        const float g00r=(ga).x, g00i=(ga).y, g01r=(ga).z, g01i=(ga).w;         \
        const float g10r=(gb).x, g10i=(gb).y, g11r=(gb).z, g11i=(gb).w;         \
        _Pragma("unroll")                                                       \
        for (int base = 0; base < 16; base += 2 * (S)) {                        \
            _Pragma("unroll")                                                   \
            for (int k = 0; k < (S); ++k) {                                     \
                const int j0 = base + k, j1 = j0 + (S);                         \
                const float ar = yr[j0], ai = yi[j0];                           \
                const float br = yr[j1], bi = yi[j1];                           \
                yr[j0] = fmaf(g00r, ar, fmaf(-g00i, ai, fmaf(g01r, br, -g01i * bi))); \
                yi[j0] = fmaf(g00r, ai, fmaf( g00i, ar, fmaf(g01r, bi,  g01i * br))); \
                yr[j1] = fmaf(g10r, ar, fmaf(-g10i, ai, fmaf(g11r, br, -g11i * bi))); \
                yi[j1] = fmaf(g10r, ai, fmaf( g10i, ar, fmaf(g11r, bi,  g11i * br))); \
            }                                                                   \
        }                                                                       \
    } while (0)

__global__ __launch_bounds__(256, 6) void qnn_fused(const float* __restrict__ x,
                                                    const float* __restrict__ params,
                                                    const float* __restrict__ fc_w,
                                                    const float* __restrict__ fc_b,
                                                    float* __restrict__ out) {
    __shared__ float cons[84];

    const int t = blockIdx.x * 256 + threadIdx.x;

    // Issue loads first (4 x dwordx4, 64 B/thread).
    const float4* xp = (const float4*)(x + (size_t)t * 16);
    float4 v0 = xp[0], v1 = xp[1], v2 = xp[2], v3 = xp[3];

    // Thread 0 computes shared constants while loads are in flight.
    if (threadIdx.x == 0) {
        for (int q = 0; q < 4; ++q) {
            float hx = 0.5f * params[q * 3 + 0];
            float hy = 0.5f * params[q * 3 + 1];
            float hz = 0.5f * params[q * 3 + 2];
            float cx = cosf(hx), sx = sinf(hx);
            float cy = cosf(hy), sy = sinf(hy);
            float cz = cosf(hz), sz = sinf(hz);
            float A = cy * cx, B = sy * sx, C = sy * cx, D = cy * sx;
            float* g = cons + q * 8;
            g[0] =  cz * A + sz * B;   // g00 re
            g[1] =  cz * B - sz * A;   // g00 im
            g[2] = -cz * C - sz * D;   // g01 re
            g[3] =  sz * C - cz * D;   // g01 im
            g[4] =  cz * C + sz * D;   // g10 re
            g[5] =  sz * C - cz * D;   // g10 im
            g[6] =  cz * A + sz * B;   // g11 re
            g[7] =  sz * A - cz * B;   // g11 im
        }
        // wv[c][q(o)] = sum_w fc_w[c,w] * zsign(o,w);  q = p01 o p12 o p23
        for (int o = 0; o < 16; ++o) {
            int j = qnn_cnot_perm(qnn_cnot_perm(qnn_cnot_perm(o, 2, 3), 1, 2), 0, 1);
            for (int c = 0; c < 3; ++c) {
                float s = 0.f;
                for (int ww = 0; ww < 4; ++ww) {
                    float z = 1.f - 2.f * (float)((o >> (3 - ww)) & 1);
                    s += fc_w[c * 4 + ww] * z;
                }
                cons[32 + c * 16 + j] = s;
            }
        }
        for (int c = 0; c < 3; ++c) cons[80 + c] = fc_b[c];
    }
    __syncthreads();

    float xv[16] = {v0.x, v0.y, v0.z, v0.w, v1.x, v1.y, v1.z, v1.w,
                    v2.x, v2.y, v2.z, v2.w, v3.x, v3.y, v3.z, v3.w};

    // ||x||^2 as 4 independent 4-deep chains + tree combine.
    float n2;
    {
        float s0 = xv[0] * xv[0], s1 = xv[1] * xv[1];
        float s2 = xv[2] * xv[2], s3 = xv[3] * xv[3];
#pragma unroll
        for (int k = 1; k < 4; ++k) {
            s0 = fmaf(xv[4 * k + 0], xv[4 * k + 0], s0);
            s1 = fmaf(xv[4 * k + 1], xv[4 * k + 1], s1);
            s2 = fmaf(xv[4 * k + 2], xv[4 * k + 2], s2);
            s3 = fmaf(xv[4 * k + 3], xv[4 * k + 3], s3);
        }
        n2 = (s0 + s1) + (s2 + s3);
    }

    float yr[16], yi[16];
    // Stage qubit 0 (stride 8), real input; xv dies here.
    {
        const float4 ga = *(const float4*)&cons[0];
        const float4 gb = *(const float4*)&cons[4];
#pragma unroll
        for (int k = 0; k < 8; ++k) {
            const float a = xv[k], b = xv[k + 8];
            yr[k]     = fmaf(ga.x, a, ga.z * b);
            yi[k]     = fmaf(ga.y, a, ga.w * b);
            yr[k + 8] = fmaf(gb.x, a, gb.z * b);
            yi[k + 8] = fmaf(gb.y, a, gb.w * b);
        }
    }
    {
        const float4 ga = *(const float4*)&cons[8],  gb = *(const float4*)&cons[12];
        QNN_CSTAGE(4, ga, gb);   // qubit 1
    }
    {
        const float4 ga = *(const float4*)&cons[16], gb = *(const float4*)&cons[20];
        QNN_CSTAGE(2, ga, gb);   // qubit 2
    }
    {
        const float4 ga = *(const float4*)&cons[24], gb = *(const float4*)&cons[28];
        QNN_CSTAGE(1, ga, gb);   // qubit 3
    }

    // probs -> 6 split accumulators (8-deep chains), wv via float4 LDS reads.
    float a0 = 0.f, a1 = 0.f, a2 = 0.f;  // j-blocks 0, 8
    float b0 = 0.f, b1 = 0.f, b2 = 0.f;  // j-blocks 4, 12
#pragma unroll
    for (int jb = 0; jb < 4; ++jb) {
        const int j = jb * 4;
        const float4 w0 = *(const float4*)&cons[32 + j];
        const float4 w1 = *(const float4*)&cons[48 + j];
        const float4 w2 = *(const float4*)&cons[64 + j];
        float p[4];
#pragma unroll
        for (int k = 0; k < 4; ++k)
            p[k] = fmaf(yr[j + k], yr[j + k], yi[j + k] * yi[j + k]);
        if ((jb & 1) == 0) {
            a0 = fmaf(w0.x, p[0], fmaf(w0.y, p[1], fmaf(w0.z, p[2], fmaf(w0.w, p[3], a0))));
            a1 = fmaf(w1.x, p[0], fmaf(w1.y, p[1], fmaf(w1.z, p[2], fmaf(w1.w, p[3], a1))));
            a2 = fmaf(w2.x, p[0], fmaf(w2.y, p[1], fmaf(w2.z, p[2], fmaf(w2.w, p[3], a2))));
        } else {
            b0 = fmaf(w0.x, p[0], fmaf(w0.y, p[1], fmaf(w0.z, p[2], fmaf(w0.w, p[3], b0))));
            b1 = fmaf(w1.x, p[0], fmaf(w1.y, p[1], fmaf(w1.z, p[2], fmaf(w1.w, p[3], b1))));
            b2 = fmaf(w2.x, p[0], fmaf(w2.y, p[1], fmaf(w2.z, p[2], fmaf(w2.w, p[3], b2))));
        }
    }

    const float inv = __builtin_amdgcn_rcpf(n2);  // |rel err| ~1e-7, threshold 3.7e-2
    float* o = out + (size_t)t * 3;
    o[0] = fmaf(a0 + b0, inv, cons[80]);
    o[1] = fmaf(a1 + b1, inv, cons[81]);
    o[2] = fmaf(a2 + b2, inv, cons[82]);
}

extern "C" void kernel_launch(void* const* d_in, const int* in_sizes, int n_in,
                              void* d_out, int out_size, void* d_ws, size_t ws_size,
                              hipStream_t stream) {
    (void)in_sizes; (void)n_in; (void)out_size; (void)d_ws; (void)ws_size;
    const float* x      = (const float*)d_in[0];
    const float* params = (const float*)d_in[1];
    const float* fc_w   = (const float*)d_in[2];
    const float* fc_b   = (const float*)d_in[3];
    float* out = (float*)d_out;

    qnn_fused<<<QNN_BATCH / 256, 256, 0, stream>>>(x, params, fc_w, fc_b, out);
}